// Round 6
// baseline (314.783 us; speedup 1.0000x reference)
//
#include <hip/hip_runtime.h>
#include <hip/hip_bf16.h>
#include <stdint.h>

#define B_ROWS 16384
#define D_K    2048
#define C_COLS 1000
#define C_PAD  1024
#define EPS_D2 1e-12f

// GEMM geometry: 256x256 tile, BK=32, 8 waves (2M x 4N), 4-deep LDS ring.
#define BM 256
#define BN 256
#define BK 32
#define NT (D_K / BK)          // 64 K-tiles
#define BUF_BYTES 32768        // A 16K + B 16K per K-tile
#define NBUF 4                 // ring depth (128 KiB LDS total)

typedef __attribute__((ext_vector_type(8))) short bf16x8;
typedef __attribute__((ext_vector_type(4))) float f32x4;

__device__ __forceinline__ void async16(void* lds, const void* g) {
    __builtin_amdgcn_global_load_lds(
        (const __attribute__((address_space(1))) unsigned int*)g,
        (__attribute__((address_space(3))) unsigned int*)lds,
        16, 0, 0);
}

// 4 f32 -> 4 bf16 (RNE) packed into uint2
__device__ __forceinline__ uint2 pack_bf16x4(float4 v) {
    union { __hip_bfloat162 h; uint32_t u; } a, b;
    a.h = __float22bfloat162_rn(make_float2(v.x, v.y));
    b.h = __float22bfloat162_rn(make_float2(v.z, v.w));
    uint2 r; r.x = a.u; r.y = b.u; return r;
}

// accumulate sum of squares of 8 bf16 (as f32) into *p.
// bf16 hi-half bitmask trick: both halves of a packed u32 are f32 bitcasts.
__device__ __forceinline__ void acc_sq(float* p, bf16x8 v) {
    union { bf16x8 s; uint32_t u[4]; } c; c.s = v;
    #pragma unroll
    for (int j = 0; j < 4; ++j) {
        float lo = __uint_as_float(c.u[j] << 16);
        float hi = __uint_as_float(c.u[j] & 0xffff0000u);
        *p += lo * lo;
        *p += hi * hi;
    }
}

// Wave-per-row prep: fp32 -> bf16 (RNE). Sum-of-squares + reduce ONLY for
// w-rows (68 blocks); x-rows (4288 blocks) are pure load/cvt/store
// (x2 is computed inside the GEMM from the bf16 A-fragments).
__global__ __launch_bounds__(256) void prep_all(
    const float* __restrict__ x, const float* __restrict__ w,
    __hip_bfloat16* __restrict__ xb, __hip_bfloat16* __restrict__ wb,
    float* __restrict__ x2, float* __restrict__ w2) {
    const int t = threadIdx.x;
    const int wave = t >> 6;
    const int lane = t & 63;
    const int row = blockIdx.x * 4 + wave;
    const bool isx = (row < B_ROWS);

    const float* src;
    uint4* dst;
    float* norm_out = nullptr;
    bool valid;
    if (isx) {
        src = x + (size_t)row * D_K;
        dst = (uint4*)(xb + (size_t)row * D_K);
        valid = true;
    } else {
        int c = row - B_ROWS;
        src = w + (size_t)c * D_K;
        dst = (uint4*)(wb + (size_t)c * D_K);
        norm_out = w2 + c;
        valid = (c < C_COLS);
    }

    float4 v[8];
    if (valid) {
        const float4* s4 = (const float4*)src;
        #pragma unroll
        for (int i = 0; i < 4; i++) {
            v[2 * i]     = s4[2 * lane + 128 * i];
            v[2 * i + 1] = s4[2 * lane + 1 + 128 * i];
        }
    } else {
        #pragma unroll
        for (int i = 0; i < 8; i++) v[i] = make_float4(0.f, 0.f, 0.f, 0.f);
    }

    #pragma unroll
    for (int i = 0; i < 4; i++) {
        uint2 a = pack_bf16x4(v[2 * i]);
        uint2 b = pack_bf16x4(v[2 * i + 1]);
        uint4 p; p.x = a.x; p.y = a.y; p.z = b.x; p.w = b.y;
        dst[lane + 64 * i] = p;
    }

    if (!isx) {   // w-rows only: sum-of-squares + wave reduce
        float ss = 0.f;
        #pragma unroll
        for (int i = 0; i < 8; i++)
            ss += v[i].x * v[i].x + v[i].y * v[i].y + v[i].z * v[i].z + v[i].w * v[i].w;
        #pragma unroll
        for (int off = 32; off > 0; off >>= 1) ss += __shfl_down(ss, off, 64);
        if (lane == 0 && valid) *norm_out = ss;
    }
}

// 256x256 tile, BK=32, 512 threads = 8 waves (2Mx4N), wave tile 128x64.
// 4-deep LDS ring, distance-3 global_load_lds prefetch, counted vmcnt(8),
// XOR chunk swizzle (0 conflicts). x2 computed in-kernel: wave wn squares
// its A-frags on tiles t with (t&3)==wn (each element once block-wide),
// fq-reduced by shfl_xor, wn-summed via 4KB LDS scratch in the epilogue.
__global__ __launch_bounds__(512, 2) void dml_gemm(
    const __hip_bfloat16* __restrict__ A,   // [B_ROWS, D_K] bf16
    const __hip_bfloat16* __restrict__ Bm,  // [C_PAD, D_K] bf16 (padded)
    const float* __restrict__ x2, const float* __restrict__ w2,
    const float* __restrict__ scales, float* __restrict__ out)
{
    __shared__ __align__(16) char smem[NBUF * BUF_BYTES];   // 131072 B

    const int tid  = threadIdx.x;
    const int wave = tid >> 6;
    const int lane = tid & 63;
    const int wm = wave >> 2;     // 0..1
    const int wn = wave & 3;      // 0..3

    // XCD-chunked mapping: 256 blocks = 1/CU; XCD x owns m-tiles [8x, 8x+8) x all 4 n.
    const int id  = blockIdx.x;
    const int xcd = id & 7;
    const int j5  = id >> 3;
    const int m0  = (xcd * 8 + (j5 & 7)) * BM;
    const int n0  = (j5 >> 3) * BN;

    // ---- staging geometry: 1024 16B-chunks per operand per K-tile; 2 per thread.
    // chunk L: row r = L>>2, stored pos c = L&3 holds global k-chunk g = c ^ ((r>>1)&3)
    const int L0 = tid, L1 = tid + 512;
    const int r0 = L0 >> 2, g0 = (L0 & 3) ^ ((r0 >> 1) & 3);
    const int r1 = L1 >> 2, g1 = (L1 & 3) ^ ((r1 >> 1) & 3);
    const __hip_bfloat16* pA0 = A  + (size_t)(m0 + r0) * D_K + g0 * 8;
    const __hip_bfloat16* pA1 = A  + (size_t)(m0 + r1) * D_K + g1 * 8;
    const __hip_bfloat16* pB0 = Bm + (size_t)(n0 + r0) * D_K + g0 * 8;
    const __hip_bfloat16* pB1 = Bm + (size_t)(n0 + r1) * D_K + g1 * 8;
    char* ldA0 = smem + L0 * 16;
    char* ldA1 = smem + L1 * 16;
    char* ldB0 = smem + 16384 + L0 * 16;
    char* ldB1 = smem + 16384 + L1 * 16;

    // ---- fragment read ptrs (swizzled): chunk = fq ^ ((fr>>1)&3)
    const int fr  = lane & 15;
    const int fq  = lane >> 4;
    const int fsw = (fr >> 1) & 3;
    const char* fA = smem + (wm * 128 + fr) * 64 + (fq ^ fsw) * 16;
    const char* fB = smem + 16384 + (wn * 64 + fr) * 64 + (fq ^ fsw) * 16;

    f32x4 acc[8][4] = {};
    float p2[8] = {0.f, 0.f, 0.f, 0.f, 0.f, 0.f, 0.f, 0.f};   // x2 partials

    // ---- prologue: stage K-tiles 0..2 (12 loads/thread), retire tile 0.
    #pragma unroll
    for (int tgt = 0; tgt < 3; ++tgt) {
        const int sbo = tgt * BUF_BYTES;
        async16(ldA0 + sbo, pA0 + tgt * BK);
        async16(ldA1 + sbo, pA1 + tgt * BK);
        async16(ldB0 + sbo, pB0 + tgt * BK);
        async16(ldB1 + sbo, pB1 + tgt * BK);
    }
    asm volatile("s_waitcnt vmcnt(8)" ::: "memory");
    __builtin_amdgcn_s_barrier();
    __builtin_amdgcn_sched_barrier(0);

    // ---- main loop: tile t reads buf[t&3], stages tile t+3 into buf[(t+3)&3].
    #pragma unroll 1
    for (int t = 0; t < NT; ++t) {
        const int bo  = (t & 3) * BUF_BYTES;
        const int tgt = t + 3;
        const bool do_stage = (tgt < NT);
        const int sbo = (tgt & 3) * BUF_BYTES;
        const bool sqact = ((t & 3) == wn);   // wave-uniform

        // phase 1: issue A-prefetch; read B frags + A frags mh=0
        if (do_stage) {
            async16(ldA0 + sbo, pA0 + tgt * BK);
            async16(ldA1 + sbo, pA1 + tgt * BK);
        }
        bf16x8 b[4], a[4];
        #pragma unroll
        for (int q = 0; q < 4; ++q) b[q] = *(const bf16x8*)(fB + bo + q * 1024);
        #pragma unroll
        for (int i = 0; i < 4; ++i) a[i] = *(const bf16x8*)(fA + bo + i * 1024);
        if (sqact) {
            #pragma unroll
            for (int i = 0; i < 4; ++i) acc_sq(&p2[i], a[i]);
        }
        __builtin_amdgcn_s_setprio(1);
        #pragma unroll
        for (int i = 0; i < 4; ++i)
            #pragma unroll
            for (int q = 0; q < 4; ++q)
                acc[i][q] = __builtin_amdgcn_mfma_f32_16x16x32_bf16(a[i], b[q], acc[i][q], 0, 0, 0);
        __builtin_amdgcn_s_setprio(0);

        // phase 2: issue B-prefetch; A frags mh=1
        if (do_stage) {
            async16(ldB0 + sbo, pB0 + tgt * BK);
            async16(ldB1 + sbo, pB1 + tgt * BK);
        }
        #pragma unroll
        for (int i = 0; i < 4; ++i) a[i] = *(const bf16x8*)(fA + bo + (4 + i) * 1024);
        if (sqact) {
            #pragma unroll
            for (int i = 0; i < 4; ++i) acc_sq(&p2[4 + i], a[i]);
        }
        __builtin_amdgcn_s_setprio(1);
        #pragma unroll
        for (int i = 0; i < 4; ++i)
            #pragma unroll
            for (int q = 0; q < 4; ++q)
                acc[4 + i][q] = __builtin_amdgcn_mfma_f32_16x16x32_bf16(a[i], b[q], acc[4 + i][q], 0, 0, 0);
        __builtin_amdgcn_s_setprio(0);

        // checkpoint: retire next tile's staging (counted, never 0 until tail).
        if (t < NT - 3)       asm volatile("s_waitcnt vmcnt(8)" ::: "memory");
        else if (t == NT - 3) asm volatile("s_waitcnt vmcnt(4)" ::: "memory");
        else if (t == NT - 2) asm volatile("s_waitcnt vmcnt(0)" ::: "memory");
        if (t < NT - 1) {
            __builtin_amdgcn_s_barrier();
            __builtin_amdgcn_sched_barrier(0);
        }
    }

    // ---- x2 assembly: reduce p2 over fq (k-slices), publish per-wn partials
    // to LDS scratch at smem[0..4K) (buf0: quiesced — all waves passed the
    // end-of-t=62 barrier; t=63 touches only buf3), then sum the 4 wn slices.
    #pragma unroll
    for (int mi = 0; mi < 8; ++mi) {
        p2[mi] += __shfl_xor(p2[mi], 16, 64);
        p2[mi] += __shfl_xor(p2[mi], 32, 64);
    }
    float* smx = (float*)smem;            // [4][256] : [wn][local row]
    if (fq == 0) {
        #pragma unroll
        for (int mi = 0; mi < 8; ++mi)
            smx[wn * 256 + wm * 128 + mi * 16 + fr] = p2[mi];
    }
    __syncthreads();

    // ---- epilogue: -s*sqrt(max(x2+w2-2*acc, eps)); direct stores.
    // C/D layout: col = lane&15 (n-side), row = (lane>>4)*4 + reg (m-side).
    const float s = scales[0];
    const int colb = n0 + wn * 64 + fr;
    const int rowb = m0 + wm * 128 + fq * 4;

    float w2v[4];
    #pragma unroll
    for (int q = 0; q < 4; ++q) w2v[q] = w2[colb + q * 16];

    #pragma unroll
    for (int i = 0; i < 8; ++i) {
        float x2v[4];
        #pragma unroll
        for (int r = 0; r < 4; ++r) {
            const int rl = wm * 128 + i * 16 + fq * 4 + r;
            x2v[r] = smx[rl] + smx[256 + rl] + smx[512 + rl] + smx[768 + rl];
        }
        #pragma unroll
        for (int q = 0; q < 4; ++q) {
            if (colb + q * 16 < C_COLS) {
                float* orow = out + (size_t)(rowb + i * 16) * C_COLS + colb + q * 16;
                #pragma unroll
                for (int r = 0; r < 4; ++r) {
                    float d2 = x2v[r] + w2v[q] - 2.0f * acc[i][q][r];
                    d2 = fmaxf(d2, EPS_D2);
                    orow[(size_t)r * C_COLS] = -s * __builtin_sqrtf(d2);
                }
            }
        }
    }
}

extern "C" void kernel_launch(void* const* d_in, const int* in_sizes, int n_in,
                              void* d_out, int out_size, void* d_ws, size_t ws_size,
                              hipStream_t stream) {
    const float* x      = (const float*)d_in[0];
    const float* w      = (const float*)d_in[1];
    const float* scales = (const float*)d_in[2];
    float* out = (float*)d_out;

    char* ws = (char*)d_ws;
    __hip_bfloat16* xb = (__hip_bfloat16*)ws;                                  // 67,108,864 B
    __hip_bfloat16* wb = (__hip_bfloat16*)(ws + (size_t)B_ROWS * D_K * 2);     //  4,194,304 B
    float* x2 = (float*)(ws + (size_t)B_ROWS * D_K * 2 + (size_t)C_PAD * D_K * 2);
    float* w2 = x2 + B_ROWS;

    prep_all<<<dim3((B_ROWS + C_PAD) / 4), dim3(256), 0, stream>>>(x, w, xb, wb, x2, w2);
    dml_gemm<<<dim3((B_ROWS / BM) * (C_PAD / BN)), dim3(512), 0, stream>>>(xb, wb, x2, w2, scales, out);
}

// Round 7
// 294.281 us; speedup vs baseline: 1.0697x; 1.0697x over previous
//
#include <hip/hip_runtime.h>
#include <hip/hip_bf16.h>
#include <stdint.h>

#define B_ROWS 16384
#define D_K    2048
#define C_COLS 1000
#define C_PAD  1024
#define EPS_D2 1e-12f

// GEMM geometry: 256x256 tile, BK=32, 8 waves (2M x 4N).
// A: staged in-kernel from fp32 x (reg cvt -> ds_write), 2-deep LDS ring.
// B: bf16 gload_lds DMA, 4-deep ring, distance-3 prefetch.
// LDS: A = smem[0..32K) (2 x 16K), B = smem[32K..96K) (4 x 16K).
#define BM 256
#define BN 256
#define BK 32
#define NT (D_K / BK)          // 64 K-tiles

typedef __attribute__((ext_vector_type(8))) short bf16x8;
typedef __attribute__((ext_vector_type(4))) float f32x4;

__device__ __forceinline__ void async16(void* lds, const void* g) {
    __builtin_amdgcn_global_load_lds(
        (const __attribute__((address_space(1))) unsigned int*)g,
        (__attribute__((address_space(3))) unsigned int*)lds,
        16, 0, 0);
}

// 4 f32 -> 4 bf16 (RNE) packed into uint2
__device__ __forceinline__ uint2 pack_bf16x4(float4 v) {
    union { __hip_bfloat162 h; uint32_t u; } a, b;
    a.h = __float22bfloat162_rn(make_float2(v.x, v.y));
    b.h = __float22bfloat162_rn(make_float2(v.z, v.w));
    uint2 r; r.x = a.u; r.y = b.u; return r;
}

__device__ __forceinline__ float sq4(float4 v) {
    return v.x * v.x + v.y * v.y + v.z * v.z + v.w * v.w;
}

// w-only prep: fp32 -> bf16 (RNE) + sum-of-squares. 256 blocks x 4 rows.
// Rows >= C_COLS zero-filled (B padding).
__global__ __launch_bounds__(256) void prep_w(
    const float* __restrict__ w, __hip_bfloat16* __restrict__ wb,
    float* __restrict__ w2) {
    const int t = threadIdx.x;
    const int wave = t >> 6;
    const int lane = t & 63;
    const int c = blockIdx.x * 4 + wave;
    const bool valid = (c < C_COLS);

    const float* src = w + (size_t)c * D_K;
    uint4* dst = (uint4*)(wb + (size_t)c * D_K);

    float4 v[8];
    if (valid) {
        const float4* s4 = (const float4*)src;
        #pragma unroll
        for (int i = 0; i < 4; i++) {
            v[2 * i]     = s4[2 * lane + 128 * i];
            v[2 * i + 1] = s4[2 * lane + 1 + 128 * i];
        }
    } else {
        #pragma unroll
        for (int i = 0; i < 8; i++) v[i] = make_float4(0.f, 0.f, 0.f, 0.f);
    }

    float ss = 0.f;
    #pragma unroll
    for (int i = 0; i < 8; i++) ss += sq4(v[i]);

    #pragma unroll
    for (int i = 0; i < 4; i++) {
        uint2 a = pack_bf16x4(v[2 * i]);
        uint2 b = pack_bf16x4(v[2 * i + 1]);
        uint4 p; p.x = a.x; p.y = a.y; p.z = b.x; p.w = b.y;
        dst[lane + 64 * i] = p;
    }

    #pragma unroll
    for (int off = 32; off > 0; off >>= 1) ss += __shfl_down(ss, off, 64);
    if (lane == 0 && valid) w2[c] = ss;
}

// 256x256 tile, BK=32, 512 threads = 8 waves (2Mx4N), wave tile 128x64.
// A staged from fp32 x: per tile, 4 dwordx4 loads (issued 1 tile ahead,
// compiler-counted waits), cvt+2x ds_write_b128 at tile top; x2 computed
// exactly (fp32) as a side product, reduced via 1KB LDS scratch at the end.
// B: gload_lds 4-deep ring, manual vmcnt(6)/(4) retire ladder.
// Explicit lgkmcnt(0) before each barrier publishes the cvt ds_writes.
__global__ __launch_bounds__(512, 2) void dml_gemm(
    const float* __restrict__ X,            // [B_ROWS, D_K] fp32
    const __hip_bfloat16* __restrict__ Bm,  // [C_PAD, D_K] bf16 (padded)
    const float* __restrict__ w2,
    const float* __restrict__ scales, float* __restrict__ out)
{
    __shared__ __align__(16) char smem[98304];   // A 32K + B 64K

    const int tid  = threadIdx.x;
    const int wave = tid >> 6;
    const int lane = tid & 63;
    const int wm = wave >> 2;     // 0..1
    const int wn = wave & 3;      // 0..3

    // XCD-chunked mapping: the 4 n-blocks sharing an A-panel land on one XCD.
    const int id  = blockIdx.x;
    const int xcd = id & 7;
    const int j5  = id >> 3;
    const int m0  = (xcd * 8 + (j5 & 7)) * BM;
    const int n0  = (j5 >> 3) * BN;

    // ---- staging geometry: 1024 16B-chunks per operand per K-tile; 2/thread.
    // chunk L: row r = L>>2, stored pos c = L&3 holds global k-chunk g = c ^ ((r>>1)&3)
    const int L0 = tid, L1 = tid + 512;
    const int r0 = L0 >> 2, g0 = (L0 & 3) ^ ((r0 >> 1) & 3);
    const int r1 = L1 >> 2, g1 = (L1 & 3) ^ ((r1 >> 1) & 3);
    const float* gAf0 = X + (size_t)(m0 + r0) * D_K + g0 * 8;   // fp32 source
    const float* gAf1 = X + (size_t)(m0 + r1) * D_K + g1 * 8;
    const __hip_bfloat16* gB0 = Bm + (size_t)(n0 + r0) * D_K + g0 * 8;
    const __hip_bfloat16* gB1 = Bm + (size_t)(n0 + r1) * D_K + g1 * 8;
    char* ldB0 = smem + 32768 + L0 * 16;
    char* ldB1 = smem + 32768 + L1 * 16;

    // ---- fragment read ptrs (swizzled): chunk = fq ^ ((fr>>1)&3)
    const int fr  = lane & 15;
    const int fq  = lane >> 4;
    const int fsw = (fr >> 1) & 3;
    const char* fA = smem + (wm * 128 + fr) * 64 + (fq ^ fsw) * 16;          // + (t&1)*16384
    const char* fB = smem + 32768 + (wn * 64 + fr) * 64 + (fq ^ fsw) * 16;   // + (t&3)*16384

    f32x4 acc[8][4] = {};
    float s0 = 0.f, s1 = 0.f;     // x2 partials for rows r0, r1

    // ---- prologue ----
    float4 va0, va1, va2, va3;    // A(t+1) fp32 regs (32 B/thread)
    {
        const float4* q0 = (const float4*)(gAf0);
        const float4* q1 = (const float4*)(gAf1);
        va0 = q0[0]; va1 = q0[1]; va2 = q1[0]; va3 = q1[1];     // A(0)
        const float4* p0 = (const float4*)(gAf0 + 32);
        const float4* p1 = (const float4*)(gAf1 + 32);
        float4 vb0 = p0[0], vb1 = p0[1], vb2 = p1[0], vb3 = p1[1]; // A(1)
        // B tiles 0..2
        async16(ldB0 + 0,     gB0);        async16(ldB1 + 0,     gB1);
        async16(ldB0 + 16384, gB0 + 32);   async16(ldB1 + 16384, gB1 + 32);
        async16(ldB0 + 32768, gB0 + 64);   async16(ldB1 + 32768, gB1 + 64);
        // cvt A(0) -> lsA buf0 (compiler waits its own loads)
        uint2 c0 = pack_bf16x4(va0), c1 = pack_bf16x4(va1);
        uint2 c2 = pack_bf16x4(va2), c3 = pack_bf16x4(va3);
        uint4 p; p.x = c0.x; p.y = c0.y; p.z = c1.x; p.w = c1.y;
        *(uint4*)(smem + L0 * 16) = p;
        p.x = c2.x; p.y = c2.y; p.z = c3.x; p.w = c3.y;
        *(uint4*)(smem + L1 * 16) = p;
        s0 += sq4(va0) + sq4(va1);
        s1 += sq4(va2) + sq4(va3);
        va0 = vb0; va1 = vb1; va2 = vb2; va3 = vb3;             // rotate (waits A(1))
    }
    asm volatile("s_waitcnt vmcnt(4)" ::: "memory");   // retire B(0); B(1),B(2) fly
    asm volatile("s_waitcnt lgkmcnt(0)" ::: "memory");
    __builtin_amdgcn_s_barrier();
    __builtin_amdgcn_sched_barrier(0);

    // ---- main loop ----
    #pragma unroll 1
    for (int t = 0; t < NT; ++t) {
        const int boA = (t & 1) * 16384;
        const int boB = (t & 3) * 16384;

        // --- staging block (outside MFMA dep chains) ---
        if (t < NT - 1) {
            // cvt + write A(t+1) (regs loaded one tile ago; compiler-counted wait)
            char* dA = smem + ((t + 1) & 1) * 16384;
            uint2 c0 = pack_bf16x4(va0), c1 = pack_bf16x4(va1);
            uint2 c2 = pack_bf16x4(va2), c3 = pack_bf16x4(va3);
            uint4 p; p.x = c0.x; p.y = c0.y; p.z = c1.x; p.w = c1.y;
            *(uint4*)(dA + L0 * 16) = p;
            p.x = c2.x; p.y = c2.y; p.z = c3.x; p.w = c3.y;
            *(uint4*)(dA + L1 * 16) = p;
            s0 += sq4(va0) + sq4(va1);
            s1 += sq4(va2) + sq4(va3);
            if (t + 2 < NT) {   // issue A(t+2) fp32 loads (before B-dma: FIFO order)
                const float4* q0 = (const float4*)(gAf0 + (t + 2) * 32);
                const float4* q1 = (const float4*)(gAf1 + (t + 2) * 32);
                va0 = q0[0]; va1 = q0[1]; va2 = q1[0]; va3 = q1[1];
            }
        }
        if (t + 3 < NT) {       // B-dma distance 3 into buf (t+3)&3
            const int sbo = ((t + 3) & 3) * 16384;
            async16(ldB0 + sbo, gB0 + (t + 3) * BK);
            async16(ldB1 + sbo, gB1 + (t + 3) * BK);
        }

        // --- compute ---
        bf16x8 b[4], a[4];
        #pragma unroll
        for (int q = 0; q < 4; ++q) b[q] = *(const bf16x8*)(fB + boB + q * 1024);
        #pragma unroll
        for (int i = 0; i < 4; ++i) a[i] = *(const bf16x8*)(fA + boA + i * 1024);
        __builtin_amdgcn_s_setprio(1);
        #pragma unroll
        for (int i = 0; i < 4; ++i)
            #pragma unroll
            for (int q = 0; q < 4; ++q)
                acc[i][q] = __builtin_amdgcn_mfma_f32_16x16x32_bf16(a[i], b[q], acc[i][q], 0, 0, 0);
        __builtin_amdgcn_s_setprio(0);
        #pragma unroll
        for (int i = 0; i < 4; ++i) a[i] = *(const bf16x8*)(fA + boA + (4 + i) * 1024);
        __builtin_amdgcn_s_setprio(1);
        #pragma unroll
        for (int i = 0; i < 4; ++i)
            #pragma unroll
            for (int q = 0; q < 4; ++q)
                acc[4 + i][q] = __builtin_amdgcn_mfma_f32_16x16x32_bf16(a[i], b[q], acc[4 + i][q], 0, 0, 0);
        __builtin_amdgcn_s_setprio(0);

        // --- end: retire B-dma (counted ladder), publish LDS, barrier ---
        if (t < NT - 3)       asm volatile("s_waitcnt vmcnt(6)" ::: "memory");
        else if (t == NT - 3) asm volatile("s_waitcnt vmcnt(4)" ::: "memory");
        if (t < NT - 1) {
            asm volatile("s_waitcnt lgkmcnt(0)" ::: "memory");
            __builtin_amdgcn_s_barrier();
            __builtin_amdgcn_sched_barrier(0);
        }
    }

    // ---- x2 assembly: 4 threads per row (lane groups of 4), LDS scratch.
    __syncthreads();                       // all frag reads done; smem reusable
    s0 += __shfl_xor(s0, 1, 64); s0 += __shfl_xor(s0, 2, 64);
    s1 += __shfl_xor(s1, 1, 64); s1 += __shfl_xor(s1, 2, 64);
    float* smx = (float*)smem;             // [256]: x2 of block-local rows
    if ((lane & 3) == 0) {
        smx[r0] = s0;                      // rows 0..127
        smx[r0 + 128] = s1;                // rows 128..255
    }
    __syncthreads();

    // ---- epilogue: -s*sqrt(max(x2+w2-2*acc, eps)); direct stores.
    // C/D layout: col = lane&15 (n-side), row = (lane>>4)*4 + reg (m-side).
    const float s = scales[0];
    const int colb = n0 + wn * 64 + fr;
    const int rowb = m0 + wm * 128 + fq * 4;

    float w2v[4];
    #pragma unroll
    for (int q = 0; q < 4; ++q) w2v[q] = w2[colb + q * 16];

    #pragma unroll
    for (int i = 0; i < 8; ++i) {
        float x2v[4];
        #pragma unroll
        for (int r = 0; r < 4; ++r)
            x2v[r] = smx[wm * 128 + i * 16 + fq * 4 + r];
        #pragma unroll
        for (int q = 0; q < 4; ++q) {
            if (colb + q * 16 < C_COLS) {
                float* orow = out + (size_t)(rowb + i * 16) * C_COLS + colb + q * 16;
                #pragma unroll
                for (int r = 0; r < 4; ++r) {
                    float d2 = x2v[r] + w2v[q] - 2.0f * acc[i][q][r];
                    d2 = fmaxf(d2, EPS_D2);
                    orow[(size_t)r * C_COLS] = -s * __builtin_sqrtf(d2);
                }
            }
        }
    }
}

extern "C" void kernel_launch(void* const* d_in, const int* in_sizes, int n_in,
                              void* d_out, int out_size, void* d_ws, size_t ws_size,
                              hipStream_t stream) {
    const float* x      = (const float*)d_in[0];
    const float* w      = (const float*)d_in[1];
    const float* scales = (const float*)d_in[2];
    float* out = (float*)d_out;

    char* ws = (char*)d_ws;
    __hip_bfloat16* wb = (__hip_bfloat16*)ws;                      // 4,194,304 B
    float* w2 = (float*)(ws + (size_t)C_PAD * D_K * 2);

    prep_w<<<dim3(C_PAD / 4), dim3(256), 0, stream>>>(w, wb, w2);
    dml_gemm<<<dim3((B_ROWS / BM) * (C_PAD / BN)), dim3(512), 0, stream>>>(x, wb, w2, scales, out);
}